// Round 2
// baseline (3171.163 us; speedup 1.0000x reference)
//
#include <hip/hip_runtime.h>
#include <hip/hip_bf16.h>

typedef __bf16 bf16x8 __attribute__((ext_vector_type(8)));
typedef __bf16 bf16x4 __attribute__((ext_vector_type(4)));
typedef float  f32x4  __attribute__((ext_vector_type(4)));

#define T_STEPS 1024

// ws layout (all bf16):
//   afrag: [mat(6)][cb(16)][kblk(8)][lane(64)][j(8)]   (393216 elems)
//     mats: 0=W_z 1=W_r 2=W 3=U_z 4=U_r 5=U
//     content = M[k][col], k = kblk*32 + (lane>>4)*8 + j, col = cb*16 + (lane&15)
//     (MFMA A-operand fragment of M^T tiles: A[m=lane&15 -> col][k])
//   gates: [t*4+g][nt(48)][lane(64)][i(4)]             (50331648 elems)
//     nt = mat*16 + cb (mat 0=z,1=r,2=h); holds x@W*+b* for
//     batch = g*16 + (lane&15), feature = cb*16 + (lane>>4)*4 + i

__global__ __launch_bounds__(256) void prep_frags(
    const float* __restrict__ Wz, const float* __restrict__ Wr, const float* __restrict__ Wh,
    const float* __restrict__ Uz, const float* __restrict__ Ur, const float* __restrict__ Uh,
    __bf16* __restrict__ afrag)
{
  int idx  = blockIdx.x * 256 + threadIdx.x;   // 1536*256 = 393216 exactly
  int mat  = idx >> 16;
  int cb   = (idx >> 12) & 15;
  int kblk = (idx >> 9) & 7;
  int l    = (idx >> 3) & 63;
  int j    = idx & 7;
  int k    = kblk * 32 + (l >> 4) * 8 + j;
  int col  = cb * 16 + (l & 15);
  const float* s = (mat == 0) ? Wz : (mat == 1) ? Wr : (mat == 2) ? Wh
                 : (mat == 3) ? Uz : (mat == 4) ? Ur : Uh;
  afrag[idx] = (__bf16)s[k * 256 + col];
}

// X-projection GEMM: gates[t,g,nt,lane,i] = (x @ W*)[batch, feature] + b*
// Block = (t,g) pair (bt = t*4+g), 4 waves; wave w handles nt = w,w+4,...,w+44.
// B operand = x^T fragments (fp32 -> bf16 inline) in regs, A streamed from afrag.
__global__ __launch_bounds__(256) void gemm_x(
    const float* __restrict__ x, const __bf16* __restrict__ afrag,
    const float* __restrict__ bz, const float* __restrict__ br, const float* __restrict__ bh,
    __bf16* __restrict__ gates)
{
  int bt = blockIdx.x;                 // t*4 + g
  int tid = threadIdx.x;
  int l = tid & 63, w = tid >> 6;
  int q = l >> 4, m15 = l & 15;

  // global batch row = t*64 + g*16 + m15 = bt*16 + m15
  const float* xrow = x + ((size_t)bt * 16 + m15) * 256 + q * 8;
  bf16x8 bfr[8];
#pragma unroll
  for (int kb = 0; kb < 8; kb++) {
    f32x4 lo = *(const f32x4*)(xrow + kb * 32);
    f32x4 hi = *(const f32x4*)(xrow + kb * 32 + 4);
    bf16x8 v;
#pragma unroll
    for (int j = 0; j < 4; j++) { v[j] = (__bf16)lo[j]; v[4 + j] = (__bf16)hi[j]; }
    bfr[kb] = v;
  }

  const bf16x8* af = (const bf16x8*)afrag;
#pragma unroll 1
  for (int jj = 0; jj < 12; jj++) {
    int nt = w + 4 * jj;
    int mat = nt >> 4, cb = nt & 15;
    f32x4 acc = {0.f, 0.f, 0.f, 0.f};
#pragma unroll
    for (int kb = 0; kb < 8; kb++)
      acc = __builtin_amdgcn_mfma_f32_16x16x32_bf16(af[(nt * 8 + kb) * 64 + l], bfr[kb], acc, 0, 0, 0);
    const float* bias = (mat == 0) ? bz : (mat == 1) ? br : bh;
    bf16x4 ov;
#pragma unroll
    for (int i = 0; i < 4; i++) {
      int f = cb * 16 + q * 4 + i;
      ov[i] = (__bf16)(acc[i] + bias[f]);
    }
    *(bf16x4*)(gates + ((size_t)bt * 48 + nt) * 256 + l * 4) = ov;
  }
}

// Recurrent kernel: 4 blocks (batch groups of 16) x 512 threads (8 waves).
// Wave w owns feature colblocks {2w, 2w+1}; U_z/U_r/U A-fragments persist in
// 192 VGPRs. h^T / (r*h)^T live in LDS in B-fragment order (conflict-free
// ds_read_b128; packed b64 write-back from the C-layout combine stage).
__global__ __launch_bounds__(512) void gru_rec(
    const __bf16* __restrict__ afrag, const __bf16* __restrict__ gates,
    const float* __restrict__ h0, float* __restrict__ out)
{
  __shared__ bf16x8 hfrag[512];    // [kblk(8)][lane(64)]
  __shared__ bf16x8 rhfrag[512];
  int g = blockIdx.x;
  int tid = threadIdx.x;
  int l = tid & 63, w = tid >> 6;
  int q = l >> 4, m15 = l & 15;

  // persistent weight A-fragments
  bf16x8 wz[2][8], wr[2][8], wu[2][8];
  const bf16x8* af = (const bf16x8*)afrag;
#pragma unroll
  for (int c = 0; c < 2; c++) {
    int cbg = 2 * w + c;
#pragma unroll
    for (int kb = 0; kb < 8; kb++) {
      wz[c][kb] = af[((3 * 16 + cbg) * 8 + kb) * 64 + l];
      wr[c][kb] = af[((4 * 16 + cbg) * 8 + kb) * 64 + l];
      wu[c][kb] = af[((5 * 16 + cbg) * 8 + kb) * 64 + l];
    }
  }

  // h state in fp32 regs: this lane owns batch m15, features 32w+16c+4q+i
  float hreg[2][4];
#pragma unroll
  for (int c = 0; c < 2; c++)
#pragma unroll
    for (int i = 0; i < 4; i++)
      hreg[c][i] = h0[32 * w + 16 * c + 4 * q + i];

  // init h^T fragment buffer (broadcast over batch); wave w fills kblk w
  {
    const float* hp = h0 + w * 32 + q * 8;
    bf16x8 hv;
#pragma unroll
    for (int j = 0; j < 8; j++) hv[j] = (__bf16)hp[j];
    hfrag[w * 64 + l] = hv;
  }
  __syncthreads();

  // packed write slots (bf16x4 units): feature group 32w+16c+4q -> kblk=w,
  // dest lane' = m15 + 16*(2c + (q>>1)), half = q&1
  int wr0 = w * 128 + (m15 + 16 * (0 + (q >> 1))) * 2 + (q & 1);
  int wr1 = w * 128 + (m15 + 16 * (2 + (q >> 1))) * 2 + (q & 1);
  bf16x4* hf4  = (bf16x4*)hfrag;
  bf16x4* rhf4 = (bf16x4*)rhfrag;

#pragma unroll 1
  for (int t = 0; t < T_STEPS; t++) {
    size_t gb = ((size_t)t * 4 + g) * 48 * 256;
    bf16x4 gz0 = *(const bf16x4*)(gates + gb + (0 * 16 + 2 * w + 0) * 256 + l * 4);
    bf16x4 gz1 = *(const bf16x4*)(gates + gb + (0 * 16 + 2 * w + 1) * 256 + l * 4);
    bf16x4 gr0 = *(const bf16x4*)(gates + gb + (1 * 16 + 2 * w + 0) * 256 + l * 4);
    bf16x4 gr1 = *(const bf16x4*)(gates + gb + (1 * 16 + 2 * w + 1) * 256 + l * 4);

    // out[t] = hidden entering step t (pre-update), fp32
    {
      f32x4 o0 = {hreg[0][0], hreg[0][1], hreg[0][2], hreg[0][3]};
      f32x4 o1 = {hreg[1][0], hreg[1][1], hreg[1][2], hreg[1][3]};
      float* op = out + ((size_t)t * 64 + g * 16 + m15) * 256 + 32 * w + 4 * q;
      *(f32x4*)(op)      = o0;
      *(f32x4*)(op + 16) = o1;
    }

    // phase 1: z, r preacts  (4 MFMAs per ds_read_b128)
    f32x4 az0 = {0,0,0,0}, az1 = {0,0,0,0}, ar0 = {0,0,0,0}, ar1 = {0,0,0,0};
#pragma unroll
    for (int kb = 0; kb < 8; kb++) {
      bf16x8 hb = hfrag[kb * 64 + l];
      az0 = __builtin_amdgcn_mfma_f32_16x16x32_bf16(wz[0][kb], hb, az0, 0, 0, 0);
      az1 = __builtin_amdgcn_mfma_f32_16x16x32_bf16(wz[1][kb], hb, az1, 0, 0, 0);
      ar0 = __builtin_amdgcn_mfma_f32_16x16x32_bf16(wr[0][kb], hb, ar0, 0, 0, 0);
      ar1 = __builtin_amdgcn_mfma_f32_16x16x32_bf16(wr[1][kb], hb, ar1, 0, 0, 0);
    }
    float zv[2][4], rv[2][4];
#pragma unroll
    for (int i = 0; i < 4; i++) {
      zv[0][i] = 1.f / (1.f + __expf(-(az0[i] + (float)gz0[i])));
      zv[1][i] = 1.f / (1.f + __expf(-(az1[i] + (float)gz1[i])));
      rv[0][i] = 1.f / (1.f + __expf(-(ar0[i] + (float)gr0[i])));
      rv[1][i] = 1.f / (1.f + __expf(-(ar1[i] + (float)gr1[i])));
    }
    bf16x4 rh0, rh1;
#pragma unroll
    for (int i = 0; i < 4; i++) {
      rh0[i] = (__bf16)(rv[0][i] * hreg[0][i]);
      rh1[i] = (__bf16)(rv[1][i] * hreg[1][i]);
    }
    rhf4[wr0] = rh0;
    rhf4[wr1] = rh1;
    __syncthreads();

    // phase 2: h_bar preact from (r*h)
    bf16x4 gh0 = *(const bf16x4*)(gates + gb + (2 * 16 + 2 * w + 0) * 256 + l * 4);
    bf16x4 gh1 = *(const bf16x4*)(gates + gb + (2 * 16 + 2 * w + 1) * 256 + l * 4);
    f32x4 ah0 = {0,0,0,0}, ah1 = {0,0,0,0};
#pragma unroll
    for (int kb = 0; kb < 8; kb++) {
      bf16x8 rb = rhfrag[kb * 64 + l];
      ah0 = __builtin_amdgcn_mfma_f32_16x16x32_bf16(wu[0][kb], rb, ah0, 0, 0, 0);
      ah1 = __builtin_amdgcn_mfma_f32_16x16x32_bf16(wu[1][kb], rb, ah1, 0, 0, 0);
    }
    bf16x4 nh0, nh1;
#pragma unroll
    for (int i = 0; i < 4; i++) {
      float hb0 = 1.f - 2.f / (1.f + __expf(2.f * (ah0[i] + (float)gh0[i])));
      float hb1 = 1.f - 2.f / (1.f + __expf(2.f * (ah1[i] + (float)gh1[i])));
      hreg[0][i] = (1.f - rv[0][i]) * hreg[0][i] + zv[0][i] * hb0;   // note: (1-r), per reference
      hreg[1][i] = (1.f - rv[1][i]) * hreg[1][i] + zv[1][i] * hb1;
      nh0[i] = (__bf16)hreg[0][i];
      nh1[i] = (__bf16)hreg[1][i];
    }
    hf4[wr0] = nh0;
    hf4[wr1] = nh1;
    __syncthreads();
  }
}

extern "C" void kernel_launch(void* const* d_in, const int* in_sizes, int n_in,
                              void* d_out, int out_size, void* d_ws, size_t ws_size,
                              hipStream_t stream)
{
  const float* x  = (const float*)d_in[0];
  const float* Wh = (const float*)d_in[1];
  const float* Uh = (const float*)d_in[2];
  const float* bh = (const float*)d_in[3];
  const float* Wr = (const float*)d_in[4];
  const float* Ur = (const float*)d_in[5];
  const float* br = (const float*)d_in[6];
  const float* Wz = (const float*)d_in[7];
  const float* Uz = (const float*)d_in[8];
  const float* bz = (const float*)d_in[9];
  const float* h0 = (const float*)d_in[10];

  __bf16* afrag = (__bf16*)d_ws;
  __bf16* gates = (__bf16*)d_ws + 393216;
  if (ws_size < (size_t)(393216 + 50331648) * 2) return;  // need ~96.8 MB

  prep_frags<<<1536, 256, 0, stream>>>(Wz, Wr, Wh, Uz, Ur, Uh, afrag);
  gemm_x<<<4096, 256, 0, stream>>>(x, afrag, bz, br, bh, gates);
  gru_rec<<<4, 512, 0, stream>>>(afrag, gates, h0, (float*)d_out);
}

// Round 3
// 2228.756 us; speedup vs baseline: 1.4228x; 1.4228x over previous
//
#include <hip/hip_runtime.h>
#include <hip/hip_bf16.h>

typedef __bf16 bf16x8 __attribute__((ext_vector_type(8)));
typedef __bf16 bf16x4 __attribute__((ext_vector_type(4)));
typedef float  f32x4  __attribute__((ext_vector_type(4)));

#define T_STEPS 1024
#define LOG2E 1.4426950408889634f

// LDS-only barrier: orders ds_read/ds_write across the workgroup WITHOUT the
// vmcnt(0) drain __syncthreads() emits. Global loads/stores stay in flight
// across it and synchronize via their own data-dependency waitcnts.
#define LDS_BARRIER() asm volatile("s_waitcnt lgkmcnt(0)\n\ts_barrier" ::: "memory")

__device__ __forceinline__ float fast_sigmoid(float x) {
  float e = __builtin_amdgcn_exp2f(x * -LOG2E);
  return __builtin_amdgcn_rcpf(1.f + e);
}
__device__ __forceinline__ float fast_tanh(float x) {
  float e = __builtin_amdgcn_exp2f(x * (2.f * LOG2E));
  return 1.f - 2.f * __builtin_amdgcn_rcpf(1.f + e);
}

// ws layout (all bf16):
//   afrag: [mat(6)][cb(16)][kblk(8)][lane(64)][j(8)]   (393216 elems)
//     mats: 0=W_z 1=W_r 2=W 3=U_z 4=U_r 5=U
//     content = M[k][col], k = kblk*32 + (lane>>4)*8 + j, col = cb*16 + (lane&15)
//   gates: [t*4+g][nt(48)][lane(64)][i(4)]             (50331648 elems)
//     nt = mat*16 + cb (mat 0=z,1=r,2=h); holds x@W*+b* for
//     batch = g*16 + (lane&15), feature = cb*16 + (lane>>4)*4 + i

__global__ __launch_bounds__(256) void prep_frags(
    const float* __restrict__ Wz, const float* __restrict__ Wr, const float* __restrict__ Wh,
    const float* __restrict__ Uz, const float* __restrict__ Ur, const float* __restrict__ Uh,
    __bf16* __restrict__ afrag)
{
  int idx  = blockIdx.x * 256 + threadIdx.x;   // 1536*256 = 393216 exactly
  int mat  = idx >> 16;
  int cb   = (idx >> 12) & 15;
  int kblk = (idx >> 9) & 7;
  int l    = (idx >> 3) & 63;
  int j    = idx & 7;
  int k    = kblk * 32 + (l >> 4) * 8 + j;
  int col  = cb * 16 + (l & 15);
  const float* s = (mat == 0) ? Wz : (mat == 1) ? Wr : (mat == 2) ? Wh
                 : (mat == 3) ? Uz : (mat == 4) ? Ur : Uh;
  afrag[idx] = (__bf16)s[k * 256 + col];
}

// X-projection GEMM: block = one timestep t (1024 blocks, 4 waves).
// Each wave holds the x^T B-fragments for all 4 batch groups (128 VGPRs) and
// streams A-fragments from L2 once, reusing each across the 4 groups.
__global__ __launch_bounds__(256) void gemm_x(
    const float* __restrict__ x, const __bf16* __restrict__ afrag,
    const float* __restrict__ bz, const float* __restrict__ br, const float* __restrict__ bh,
    __bf16* __restrict__ gates)
{
  int t = blockIdx.x;                  // timestep
  int tid = threadIdx.x;
  int l = tid & 63, w = tid >> 6;
  int q = l >> 4, m15 = l & 15;

  bf16x8 bfr[4][8];
#pragma unroll
  for (int g = 0; g < 4; g++) {
    const float* xrow = x + ((size_t)t * 64 + g * 16 + m15) * 256 + q * 8;
#pragma unroll
    for (int kb = 0; kb < 8; kb++) {
      f32x4 lo = *(const f32x4*)(xrow + kb * 32);
      f32x4 hi = *(const f32x4*)(xrow + kb * 32 + 4);
      bf16x8 v;
#pragma unroll
      for (int j = 0; j < 4; j++) { v[j] = (__bf16)lo[j]; v[4 + j] = (__bf16)hi[j]; }
      bfr[g][kb] = v;
    }
  }

  const bf16x8* af = (const bf16x8*)afrag;
#pragma unroll 1
  for (int jj = 0; jj < 12; jj++) {
    int nt = w + 4 * jj;
    int mat = nt >> 4, cb = nt & 15;
    f32x4 acc[4];
#pragma unroll
    for (int g = 0; g < 4; g++) acc[g] = (f32x4){0.f, 0.f, 0.f, 0.f};
#pragma unroll
    for (int kb = 0; kb < 8; kb++) {
      bf16x8 a = af[(nt * 8 + kb) * 64 + l];
#pragma unroll
      for (int g = 0; g < 4; g++)
        acc[g] = __builtin_amdgcn_mfma_f32_16x16x32_bf16(a, bfr[g][kb], acc[g], 0, 0, 0);
    }
    const float* bias = (mat == 0) ? bz : (mat == 1) ? br : bh;
    float b4[4];
#pragma unroll
    for (int i = 0; i < 4; i++) b4[i] = bias[cb * 16 + q * 4 + i];
#pragma unroll
    for (int g = 0; g < 4; g++) {
      bf16x4 ov;
#pragma unroll
      for (int i = 0; i < 4; i++) ov[i] = (__bf16)(acc[g][i] + b4[i]);
      *(bf16x4*)(gates + (((size_t)t * 4 + g) * 48 + nt) * 256 + l * 4) = ov;
    }
  }
}

// Recurrent kernel: 4 blocks (batch groups of 16) x 512 threads (8 waves).
// Wave w owns feature colblocks {2w, 2w+1}; U_z/U_r/U A-fragments persist in
// 192 VGPRs (launch_bounds(512,2) -> 256-reg budget). h^T / (r*h)^T live in
// LDS in B-fragment order. Barriers are LDS-only (no vmcnt drain); z/r gates
// are prefetched one full step ahead, h-gates at step top (used ~1200cyc later).
__global__ __launch_bounds__(512, 2) void gru_rec(
    const __bf16* __restrict__ afrag, const __bf16* __restrict__ gates,
    const float* __restrict__ h0, float* __restrict__ out)
{
  __shared__ bf16x8 hfrag[512];    // [kblk(8)][lane(64)]
  __shared__ bf16x8 rhfrag[512];
  int g = blockIdx.x;
  int tid = threadIdx.x;
  int l = tid & 63, w = tid >> 6;
  int q = l >> 4, m15 = l & 15;

  // persistent weight A-fragments (192 VGPRs)
  bf16x8 wz[2][8], wr[2][8], wu[2][8];
  const bf16x8* af = (const bf16x8*)afrag;
#pragma unroll
  for (int c = 0; c < 2; c++) {
    int cbg = 2 * w + c;
#pragma unroll
    for (int kb = 0; kb < 8; kb++) {
      wz[c][kb] = af[((3 * 16 + cbg) * 8 + kb) * 64 + l];
      wr[c][kb] = af[((4 * 16 + cbg) * 8 + kb) * 64 + l];
      wu[c][kb] = af[((5 * 16 + cbg) * 8 + kb) * 64 + l];
    }
  }

  // h state in fp32 regs: this lane owns batch m15, features 32w+16c+4q+i
  float hreg[2][4];
#pragma unroll
  for (int c = 0; c < 2; c++)
#pragma unroll
    for (int i = 0; i < 4; i++)
      hreg[c][i] = h0[32 * w + 16 * c + 4 * q + i];

  // init h^T fragment buffer; wave w fills kblk w
  {
    const float* hp = h0 + w * 32 + q * 8;
    bf16x8 hv;
#pragma unroll
    for (int j = 0; j < 8; j++) hv[j] = (__bf16)hp[j];
    hfrag[w * 64 + l] = hv;
  }
  LDS_BARRIER();

  // packed write slots (bf16x4 units): feature group 32w+16c+4q -> kblk=w,
  // dest lane' = m15 + 16*(2c + (q>>1)), half = q&1
  int wr0 = w * 128 + (m15 + 16 * (0 + (q >> 1))) * 2 + (q & 1);
  int wr1 = w * 128 + (m15 + 16 * (2 + (q >> 1))) * 2 + (q & 1);
  bf16x4* hf4  = (bf16x4*)hfrag;
  bf16x4* rhf4 = (bf16x4*)rhfrag;

  // strength-reduced pointers (per-step stride = 4*48*256 elems)
  const size_t STRIDE = (size_t)4 * 48 * 256;
  const __bf16* gz_p = gates + ((size_t)g * 48 + (0 * 16 + 2 * w)) * 256 + l * 4;
  const __bf16* gr_p = gates + ((size_t)g * 48 + (1 * 16 + 2 * w)) * 256 + l * 4;
  const __bf16* gh_p = gates + ((size_t)g * 48 + (2 * 16 + 2 * w)) * 256 + l * 4;
  float* out_p = out + ((size_t)g * 16 + m15) * 256 + 32 * w + 4 * q;

  // prefetch t=0 z/r gates
  bf16x4 nz0 = *(const bf16x4*)(gz_p);
  bf16x4 nz1 = *(const bf16x4*)(gz_p + 256);
  bf16x4 nr0 = *(const bf16x4*)(gr_p);
  bf16x4 nr1 = *(const bf16x4*)(gr_p + 256);

#pragma unroll 1
  for (int t = 0; t < T_STEPS; t++) {
    // current-step h-gates (consumed in phase 2, ~1200 cyc from now)
    bf16x4 gh0 = *(const bf16x4*)(gh_p);
    bf16x4 gh1 = *(const bf16x4*)(gh_p + 256);
    gh_p += STRIDE;

    // out[t] = hidden entering step t (pre-update), fp32
    {
      f32x4 o0 = {hreg[0][0], hreg[0][1], hreg[0][2], hreg[0][3]};
      f32x4 o1 = {hreg[1][0], hreg[1][1], hreg[1][2], hreg[1][3]};
      *(f32x4*)(out_p)      = o0;
      *(f32x4*)(out_p + 16) = o1;
      out_p += 64 * 256;
    }

    // phase 1: z, r preacts
    f32x4 az0 = {0,0,0,0}, az1 = {0,0,0,0}, ar0 = {0,0,0,0}, ar1 = {0,0,0,0};
#pragma unroll
    for (int kb = 0; kb < 8; kb++) {
      bf16x8 hb = hfrag[kb * 64 + l];
      az0 = __builtin_amdgcn_mfma_f32_16x16x32_bf16(wz[0][kb], hb, az0, 0, 0, 0);
      az1 = __builtin_amdgcn_mfma_f32_16x16x32_bf16(wz[1][kb], hb, az1, 0, 0, 0);
      ar0 = __builtin_amdgcn_mfma_f32_16x16x32_bf16(wr[0][kb], hb, ar0, 0, 0, 0);
      ar1 = __builtin_amdgcn_mfma_f32_16x16x32_bf16(wr[1][kb], hb, ar1, 0, 0, 0);
    }
    // activations; keep z/r across barrier as bf16 packs (reg budget)
    bf16x4 zb0, zb1, rb0, rb1, rh0, rh1;
#pragma unroll
    for (int i = 0; i < 4; i++) {
      float z0 = fast_sigmoid(az0[i] + (float)nz0[i]);
      float z1 = fast_sigmoid(az1[i] + (float)nz1[i]);
      float r0 = fast_sigmoid(ar0[i] + (float)nr0[i]);
      float r1 = fast_sigmoid(ar1[i] + (float)nr1[i]);
      zb0[i] = (__bf16)z0; zb1[i] = (__bf16)z1;
      rb0[i] = (__bf16)r0; rb1[i] = (__bf16)r1;
      rh0[i] = (__bf16)(r0 * hreg[0][i]);
      rh1[i] = (__bf16)(r1 * hreg[1][i]);
    }
    rhf4[wr0] = rh0;
    rhf4[wr1] = rh1;

    // z/r gate regs now dead -> prefetch step t+1 (hidden behind ~full step)
    {
      size_t adv = (t < T_STEPS - 1) ? STRIDE : 0;
      gz_p += adv; gr_p += adv;
      nz0 = *(const bf16x4*)(gz_p);
      nz1 = *(const bf16x4*)(gz_p + 256);
      nr0 = *(const bf16x4*)(gr_p);
      nr1 = *(const bf16x4*)(gr_p + 256);
    }
    LDS_BARRIER();

    // phase 2: h_bar preact from (r*h)
    f32x4 ah0 = {0,0,0,0}, ah1 = {0,0,0,0};
#pragma unroll
    for (int kb = 0; kb < 8; kb++) {
      bf16x8 rb = rhfrag[kb * 64 + l];
      ah0 = __builtin_amdgcn_mfma_f32_16x16x32_bf16(wu[0][kb], rb, ah0, 0, 0, 0);
      ah1 = __builtin_amdgcn_mfma_f32_16x16x32_bf16(wu[1][kb], rb, ah1, 0, 0, 0);
    }
    bf16x4 nh0, nh1;
#pragma unroll
    for (int i = 0; i < 4; i++) {
      float hb0 = fast_tanh(ah0[i] + (float)gh0[i]);
      float hb1 = fast_tanh(ah1[i] + (float)gh1[i]);
      float z0 = (float)zb0[i], z1 = (float)zb1[i];
      float r0 = (float)rb0[i], r1 = (float)rb1[i];
      hreg[0][i] = (1.f - r0) * hreg[0][i] + z0 * hb0;   // (1-r), per reference
      hreg[1][i] = (1.f - r1) * hreg[1][i] + z1 * hb1;
      nh0[i] = (__bf16)hreg[0][i];
      nh1[i] = (__bf16)hreg[1][i];
    }
    hf4[wr0] = nh0;
    hf4[wr1] = nh1;
    LDS_BARRIER();
  }
}

extern "C" void kernel_launch(void* const* d_in, const int* in_sizes, int n_in,
                              void* d_out, int out_size, void* d_ws, size_t ws_size,
                              hipStream_t stream)
{
  const float* x  = (const float*)d_in[0];
  const float* Wh = (const float*)d_in[1];
  const float* Uh = (const float*)d_in[2];
  const float* bh = (const float*)d_in[3];
  const float* Wr = (const float*)d_in[4];
  const float* Ur = (const float*)d_in[5];
  const float* br = (const float*)d_in[6];
  const float* Wz = (const float*)d_in[7];
  const float* Uz = (const float*)d_in[8];
  const float* bz = (const float*)d_in[9];
  const float* h0 = (const float*)d_in[10];

  __bf16* afrag = (__bf16*)d_ws;
  __bf16* gates = (__bf16*)d_ws + 393216;
  if (ws_size < (size_t)(393216 + 50331648) * 2) return;  // need ~96.8 MB

  prep_frags<<<1536, 256, 0, stream>>>(Wz, Wr, Wh, Uz, Ur, Uh, afrag);
  gemm_x<<<1024, 256, 0, stream>>>(x, afrag, bz, br, bh, gates);
  gru_rec<<<4, 512, 0, stream>>>(afrag, gates, h0, (float*)d_out);
}

// Round 4
// 1831.293 us; speedup vs baseline: 1.7317x; 1.2170x over previous
//
#include <hip/hip_runtime.h>
#include <hip/hip_bf16.h>

typedef __bf16 bf16x8 __attribute__((ext_vector_type(8)));
typedef __bf16 bf16x4 __attribute__((ext_vector_type(4)));
typedef float  f32x4  __attribute__((ext_vector_type(4)));
typedef unsigned int u32x4 __attribute__((ext_vector_type(4)));

#define T_STEPS 1024
#define LOG2E 1.4426950408889634f

// LDS-only barrier: orders ds ops across the workgroup WITHOUT the vmcnt(0)
// drain __syncthreads() emits; global loads/stores stay in flight.
#define LDS_BARRIER() asm volatile("s_waitcnt lgkmcnt(0)\n\ts_barrier" ::: "memory")

__device__ __forceinline__ float fast_sigmoid(float x) {
  float e = __builtin_amdgcn_exp2f(x * -LOG2E);
  return __builtin_amdgcn_rcpf(1.f + e);
}
__device__ __forceinline__ float fast_tanh(float x) {
  float e = __builtin_amdgcn_exp2f(x * (2.f * LOG2E));
  return 1.f - 2.f * __builtin_amdgcn_rcpf(1.f + e);
}
// exact bf16(hi16-of-f32) -> f32 re-embedding, 1 VALU op each
__device__ __forceinline__ float bf_lo(unsigned int u) { return __uint_as_float(u << 16); }
__device__ __forceinline__ float bf_hi(unsigned int u) { return __uint_as_float(u & 0xFFFF0000u); }

// ws layout (all bf16):
//   afrag: [mat(6)][cb(16)][kblk(8)][lane(64)][j(8)]   (393216 elems)
//     mats: 0=W_z 1=W_r 2=W 3=U_z 4=U_r 5=U
//     content = M[k][col], k = kblk*32 + (lane>>4)*8 + j, col = cb*16 + (lane&15)
//   gates: [t*4+g][mat(3)][p(8)][lane(64)][c(2)][i(4)]  (50331648 elems)
//     mat 0=z,1=r,2=h; holds x@W*+b* for batch = g*16 + (lane&15),
//     feature = (2p+c)*16 + (lane>>4)*4 + i  -- i.e. MFMA C-layout, with the
//     two colblocks of a wave adjacent so one dwordx4/lane fetches both.

__global__ __launch_bounds__(256) void prep_frags(
    const float* __restrict__ Wz, const float* __restrict__ Wr, const float* __restrict__ Wh,
    const float* __restrict__ Uz, const float* __restrict__ Ur, const float* __restrict__ Uh,
    __bf16* __restrict__ afrag)
{
  int idx  = blockIdx.x * 256 + threadIdx.x;   // 1536*256 = 393216 exactly
  int mat  = idx >> 16;
  int cb   = (idx >> 12) & 15;
  int kblk = (idx >> 9) & 7;
  int l    = (idx >> 3) & 63;
  int j    = idx & 7;
  int k    = kblk * 32 + (l >> 4) * 8 + j;
  int col  = cb * 16 + (l & 15);
  const float* s = (mat == 0) ? Wz : (mat == 1) ? Wr : (mat == 2) ? Wh
                 : (mat == 3) ? Uz : (mat == 4) ? Ur : Uh;
  afrag[idx] = (__bf16)s[k * 256 + col];
}

// X-projection GEMM: block = one timestep t (1024 blocks, 4 waves).
// Each wave holds x^T B-fragments for all 4 batch groups (128 VGPRs) and
// streams A-fragments from L2 once, reusing each across the 4 groups.
__global__ __launch_bounds__(256) void gemm_x(
    const float* __restrict__ x, const __bf16* __restrict__ afrag,
    const float* __restrict__ bz, const float* __restrict__ br, const float* __restrict__ bh,
    __bf16* __restrict__ gates)
{
  int t = blockIdx.x;                  // timestep
  int tid = threadIdx.x;
  int l = tid & 63, w = tid >> 6;
  int q = l >> 4, m15 = l & 15;

  bf16x8 bfr[4][8];
#pragma unroll
  for (int g = 0; g < 4; g++) {
    const float* xrow = x + ((size_t)t * 64 + g * 16 + m15) * 256 + q * 8;
#pragma unroll
    for (int kb = 0; kb < 8; kb++) {
      f32x4 lo = *(const f32x4*)(xrow + kb * 32);
      f32x4 hi = *(const f32x4*)(xrow + kb * 32 + 4);
      bf16x8 v;
#pragma unroll
      for (int j = 0; j < 4; j++) { v[j] = (__bf16)lo[j]; v[4 + j] = (__bf16)hi[j]; }
      bfr[g][kb] = v;
    }
  }

  const bf16x8* af = (const bf16x8*)afrag;
#pragma unroll 1
  for (int jj = 0; jj < 12; jj++) {
    int nt = w + 4 * jj;
    int mat = nt >> 4, cb = nt & 15;
    f32x4 acc[4];
#pragma unroll
    for (int g = 0; g < 4; g++) acc[g] = (f32x4){0.f, 0.f, 0.f, 0.f};
#pragma unroll
    for (int kb = 0; kb < 8; kb++) {
      bf16x8 a = af[(nt * 8 + kb) * 64 + l];
#pragma unroll
      for (int g = 0; g < 4; g++)
        acc[g] = __builtin_amdgcn_mfma_f32_16x16x32_bf16(a, bfr[g][kb], acc[g], 0, 0, 0);
    }
    const float* bias = (mat == 0) ? bz : (mat == 1) ? br : bh;
    float b4[4];
#pragma unroll
    for (int i = 0; i < 4; i++) b4[i] = bias[cb * 16 + q * 4 + i];
    int p = cb >> 1, c = cb & 1;
#pragma unroll
    for (int g = 0; g < 4; g++) {
      bf16x4 ov;
#pragma unroll
      for (int i = 0; i < 4; i++) ov[i] = (__bf16)(acc[g][i] + b4[i]);
      *(bf16x4*)(gates + ((size_t)t * 4 + g) * 12288 + ((mat * 8 + p) * 64 + l) * 8 + c * 4) = ov;
    }
  }
}

// Recurrent kernel: 4 blocks (batch groups of 16) x 512 threads (8 waves).
// Wave w owns feature colblocks {2w, 2w+1}. Weight A-fragments persist in
// regs. h^T/(r*h)^T in LDS B-fragment order. Gate preacts feed MFMA as the
// C initializer (no zero-init, no post-add). All step pointers advance in
// SGPRs; lane offsets are loop-invariant 32-bit.
__global__ __launch_bounds__(512, 2) void gru_rec(
    const __bf16* __restrict__ afrag, const __bf16* __restrict__ gates,
    const float* __restrict__ h0, float* __restrict__ out)
{
  __shared__ bf16x8 hfrag[512];    // [kblk(8)][lane(64)]
  __shared__ bf16x8 rhfrag[512];
  int g = blockIdx.x;
  int tid = threadIdx.x;
  int l = tid & 63, w = tid >> 6;
  int q = l >> 4, m15 = l & 15;

  // persistent weight A-fragments (192 regs)
  bf16x8 wz[2][8], wr[2][8], wu[2][8];
  const bf16x8* af = (const bf16x8*)afrag;
#pragma unroll
  for (int c = 0; c < 2; c++) {
    int cbg = 2 * w + c;
#pragma unroll
    for (int kb = 0; kb < 8; kb++) {
      wz[c][kb] = af[((3 * 16 + cbg) * 8 + kb) * 64 + l];
      wr[c][kb] = af[((4 * 16 + cbg) * 8 + kb) * 64 + l];
      wu[c][kb] = af[((5 * 16 + cbg) * 8 + kb) * 64 + l];
    }
  }

  // h state in fp32 regs: this lane owns batch m15, features 32w+16c+4q+i
  float hreg[2][4];
#pragma unroll
  for (int c = 0; c < 2; c++)
#pragma unroll
    for (int i = 0; i < 4; i++)
      hreg[c][i] = h0[32 * w + 16 * c + 4 * q + i];

  // init h^T fragment buffer; wave w fills kblk w
  {
    const float* hp = h0 + w * 32 + q * 8;
    bf16x8 hv;
#pragma unroll
    for (int j = 0; j < 8; j++) hv[j] = (__bf16)hp[j];
    hfrag[w * 64 + l] = hv;
  }
  LDS_BARRIER();

  // packed LDS write slots (bf16x4 units): feature group 32w+16c+4q -> kblk=w,
  // dest lane' = m15 + 16*(2c + (q>>1)), half = q&1
  int wr0 = w * 128 + (m15 + 16 * (0 + (q >> 1))) * 2 + (q & 1);
  int wr1 = w * 128 + (m15 + 16 * (2 + (q >> 1))) * 2 + (q & 1);
  bf16x4* hf4  = (bf16x4*)hfrag;
  bf16x4* rhf4 = (bf16x4*)rhfrag;

  // uniform step bases (SGPR) + loop-invariant lane offsets (VGPR, 32-bit)
  const int GSTRIDE = 4 * 12288;                    // gates elems per t
  const __bf16* gt_p = gates + (size_t)g * 12288;   // uniform per block
  int go_z = ((0 * 8 + w) * 64 + l) * 8;
  int go_r = ((1 * 8 + w) * 64 + l) * 8;
  int go_h = ((2 * 8 + w) * 64 + l) * 8;
  const float* out_t = out;                          // uniform, += 64*256/t
  int oo = (g * 16 + m15) * 256 + 32 * w + 4 * q;

  // prefetch t=0 z/r gate preacts (raw bits)
  u32x4 nzu = *(const u32x4*)(gt_p + go_z);
  u32x4 nru = *(const u32x4*)(gt_p + go_r);

#pragma unroll 1
  for (int t = 0; t < T_STEPS; t++) {
    // current-step h-gates (consumed as phase-2 C-init, ~1 phase away)
    u32x4 ghu = *(const u32x4*)(gt_p + go_h);

    // out[t] = hidden entering step t (pre-update), fp32
    {
      f32x4 o0 = {hreg[0][0], hreg[0][1], hreg[0][2], hreg[0][3]};
      f32x4 o1 = {hreg[1][0], hreg[1][1], hreg[1][2], hreg[1][3]};
      *(f32x4*)(out_t + oo)      = o0;
      *(f32x4*)(out_t + oo + 16) = o1;
      out_t += 64 * 256;
    }

    // phase 1: z, r preacts; C initialized from gate preacts (exact embed)
    f32x4 az0 = {bf_lo(nzu.x), bf_hi(nzu.x), bf_lo(nzu.y), bf_hi(nzu.y)};
    f32x4 az1 = {bf_lo(nzu.z), bf_hi(nzu.z), bf_lo(nzu.w), bf_hi(nzu.w)};
    f32x4 ar0 = {bf_lo(nru.x), bf_hi(nru.x), bf_lo(nru.y), bf_hi(nru.y)};
    f32x4 ar1 = {bf_lo(nru.z), bf_hi(nru.z), bf_lo(nru.w), bf_hi(nru.w)};
#pragma unroll
    for (int kb = 0; kb < 8; kb++) {
      bf16x8 hb = hfrag[kb * 64 + l];
      az0 = __builtin_amdgcn_mfma_f32_16x16x32_bf16(wz[0][kb], hb, az0, 0, 0, 0);
      az1 = __builtin_amdgcn_mfma_f32_16x16x32_bf16(wz[1][kb], hb, az1, 0, 0, 0);
      ar0 = __builtin_amdgcn_mfma_f32_16x16x32_bf16(wr[0][kb], hb, ar0, 0, 0, 0);
      ar1 = __builtin_amdgcn_mfma_f32_16x16x32_bf16(wr[1][kb], hb, ar1, 0, 0, 0);
    }
    // activations; z kept as bf16 packs across barrier, r*h kept in f32
    float rhf[2][4];
    bf16x4 zb0, zb1, rhb0, rhb1;
#pragma unroll
    for (int i = 0; i < 4; i++) {
      float z0 = fast_sigmoid(az0[i]);
      float z1 = fast_sigmoid(az1[i]);
      float r0 = fast_sigmoid(ar0[i]);
      float r1 = fast_sigmoid(ar1[i]);
      zb0[i] = (__bf16)z0; zb1[i] = (__bf16)z1;
      rhf[0][i] = r0 * hreg[0][i];
      rhf[1][i] = r1 * hreg[1][i];
      rhb0[i] = (__bf16)rhf[0][i];
      rhb1[i] = (__bf16)rhf[1][i];
    }
    rhf4[wr0] = rhb0;
    rhf4[wr1] = rhb1;

    // z/r regs dead -> prefetch step t+1 (uniform scalar advance; clamped)
    const __bf16* gn_p = gt_p + ((t < T_STEPS - 1) ? GSTRIDE : 0);
    nzu = *(const u32x4*)(gn_p + go_z);
    nru = *(const u32x4*)(gn_p + go_r);
    gt_p = gn_p;
    LDS_BARRIER();

    // phase 2: h_bar preact from (r*h); C initialized from h-gate preacts
    f32x4 ah0 = {bf_lo(ghu.x), bf_hi(ghu.x), bf_lo(ghu.y), bf_hi(ghu.y)};
    f32x4 ah1 = {bf_lo(ghu.z), bf_hi(ghu.z), bf_lo(ghu.w), bf_hi(ghu.w)};
#pragma unroll
    for (int kb = 0; kb < 8; kb++) {
      bf16x8 rb = rhfrag[kb * 64 + l];
      ah0 = __builtin_amdgcn_mfma_f32_16x16x32_bf16(wu[0][kb], rb, ah0, 0, 0, 0);
      ah1 = __builtin_amdgcn_mfma_f32_16x16x32_bf16(wu[1][kb], rb, ah1, 0, 0, 0);
    }
    bf16x4 nh0, nh1;
#pragma unroll
    for (int i = 0; i < 4; i++) {
      float hb0 = fast_tanh(ah0[i]);
      float hb1 = fast_tanh(ah1[i]);
      float z0 = (float)zb0[i], z1 = (float)zb1[i];
      // h' = (h - r*h) + z*hbar   == (1-r)*h + z*hbar, per reference's (1-r)
      hreg[0][i] = (hreg[0][i] - rhf[0][i]) + z0 * hb0;
      hreg[1][i] = (hreg[1][i] - rhf[1][i]) + z1 * hb1;
      nh0[i] = (__bf16)hreg[0][i];
      nh1[i] = (__bf16)hreg[1][i];
    }
    hf4[wr0] = nh0;
    hf4[wr1] = nh1;
    LDS_BARRIER();
  }
}

extern "C" void kernel_launch(void* const* d_in, const int* in_sizes, int n_in,
                              void* d_out, int out_size, void* d_ws, size_t ws_size,
                              hipStream_t stream)
{
  const float* x  = (const float*)d_in[0];
  const float* Wh = (const float*)d_in[1];
  const float* Uh = (const float*)d_in[2];
  const float* bh = (const float*)d_in[3];
  const float* Wr = (const float*)d_in[4];
  const float* Ur = (const float*)d_in[5];
  const float* br = (const float*)d_in[6];
  const float* Wz = (const float*)d_in[7];
  const float* Uz = (const float*)d_in[8];
  const float* bz = (const float*)d_in[9];
  const float* h0 = (const float*)d_in[10];

  __bf16* afrag = (__bf16*)d_ws;
  __bf16* gates = (__bf16*)d_ws + 393216;
  if (ws_size < (size_t)(393216 + 50331648) * 2) return;  // need ~96.8 MB

  prep_frags<<<1536, 256, 0, stream>>>(Wz, Wr, Wh, Uz, Ur, Uh, afrag);
  gemm_x<<<1024, 256, 0, stream>>>(x, afrag, bz, br, bh, gates);
  gru_rec<<<4, 512, 0, stream>>>(afrag, gates, h0, (float*)d_out);
}